// Round 7
// baseline (408.600 us; speedup 1.0000x reference)
//
#include <hip/hip_runtime.h>
#include <hip/hip_bf16.h>
#include <stdint.h>

#define P_B 4096
#define P_N 16384
#define P_F 768
#define P_E 512
#define NKT_F 24   // 768/32 k-tiles
#define NKT_E 16   // 512/32 k-tiles
#define CPAD 776   // convert LDS row pad (bf16 elems)
#define EPAD 136   // embed epilogue LDS row pad

typedef __attribute__((ext_vector_type(8))) __bf16 bf16x8;
typedef __attribute__((ext_vector_type(4))) float f32x4;

__device__ __forceinline__ unsigned short bfbits(float x) {
    __bf16 h = (__bf16)x;
    union { __bf16 h; unsigned short u; } cv;
    cv.h = h;
    return cv.u;
}
__device__ __forceinline__ float bf2f(unsigned short u) {
    union { float f; unsigned int i; } cv;
    cv.i = ((unsigned int)u) << 16;
    return cv.f;
}
__device__ __forceinline__ float invn3(float n2) {
    const float inv = 1.0f / fmaxf(sqrtf(n2), 1e-12f);
    return inv * inv * inv;
}

// Fragment-packed layout: element (r,k) -> (((r>>4)*NKT + (k>>5))*64 +
// ((k>>3)&3)*16 + (r&15))*8 + (k&7). One wave fragment = contiguous 1KB.

// ---------------------------------------------------------------------------
// Convert+pack (+ zero-init of norm2/echo/cnt): fp32 row-major -> bf16
// fragment-packed via LDS transpose. Blocks 0..255 = X, 256..1279 = D,
// 1280..1311 = gw. Blocks 0..96 additionally zero the accumulator tail.
// ---------------------------------------------------------------------------
__global__ __launch_bounds__(256) void convert_pack_kernel(
    const float* __restrict__ X, const float* __restrict__ D,
    const float* __restrict__ gw,
    unsigned short* __restrict__ xdpk, unsigned short* __restrict__ gwpk,
    float* __restrict__ zbase)   // norm2(20480) | echo(4096) | cnt(1)
{
    __shared__ unsigned short T[16 * CPAD];
    const int tid = threadIdx.x;
    const int rb = blockIdx.x;          // 0..1311

    if (rb < 97) {
        const int z = rb * 256 + tid;
        if (z < P_B + P_N + P_B + 1) zbase[z] = 0.0f;
    }

    const float* src;
    unsigned short* dstbase;
    if (rb < 256)       { src = X  + (size_t)rb * 16 * P_F;          dstbase = xdpk + (size_t)rb * NKT_F * 512; }
    else if (rb < 1280) { src = D  + (size_t)(rb - 256) * 16 * P_F;  dstbase = xdpk + (size_t)rb * NKT_F * 512; }
    else                { src = gw + (size_t)(rb - 1280) * 16 * P_F; dstbase = gwpk + (size_t)(rb - 1280) * NKT_F * 512; }

#pragma unroll
    for (int it = 0; it < 12; ++it) {
        const int flat = it * 1024 + tid * 4;
        const int row = flat / P_F;
        const int col = flat - row * P_F;
        const float4 v = *(const float4*)(src + (size_t)row * P_F + col);
        unsigned short* t = &T[row * CPAD + col];
        t[0] = bfbits(v.x); t[1] = bfbits(v.y); t[2] = bfbits(v.z); t[3] = bfbits(v.w);
    }
    __syncthreads();

#pragma unroll
    for (int it = 0; it < 6; ++it) {
        const int m = it * 256 + tid;
        const int kt = m >> 6;          // 0..23
        const int lane = m & 63;
        const int r = lane & 15;
        const int k = kt * 32 + (lane >> 4) * 8;
        const uint4 frag = *(const uint4*)(&T[r * CPAD + k]);
        *(uint4*)(dstbase + (size_t)(kt * 64 + lane) * 8) = frag;
    }
}

// ---------------------------------------------------------------------------
// Embed (packed, XCD-swizzled): emb = xd·gw^T + gb. Barrier-free K-loop.
// bid&7 = XCD owns 20 rowTiles x all 4 colTiles -> A-slab (3.9MB) read ~once
// per XCD; gwpk (786KB) L2-resident. Epilogue: LDS transpose -> coalesced
// packed stores + per-row sum-of-squares.
// ---------------------------------------------------------------------------
__global__ __launch_bounds__(256, 3) void embed_pk_kernel(
    const unsigned short* __restrict__ xdpk, const unsigned short* __restrict__ gwpk,
    const float* __restrict__ gb,
    unsigned short* __restrict__ embpk, float* __restrict__ norm2)
{
    __shared__ unsigned short Es[128 * EPAD];
    const int tid = threadIdx.x, lane = tid & 63, wave = tid >> 6;
    const int q = lane >> 4, c = lane & 15;
    const int bid = blockIdx.x;                 // 0..639
    const int xcd = bid & 7;
    const int idx = bid >> 3;                   // 0..79
    const int rowTile = xcd * 20 + idx % 20;    // 0..159
    const int colTile = idx / 20;               // 0..3
    const int rbA0 = rowTile * 8 + (wave >> 1) * 4;
    const int rbB0 = colTile * 8 + (wave & 1) * 4;

    const unsigned short* pa[4];
    const unsigned short* pb[4];
#pragma unroll
    for (int i = 0; i < 4; i++)
        pa[i] = xdpk + ((size_t)(rbA0 + i) * NKT_F * 64 + lane) * 8;
#pragma unroll
    for (int j = 0; j < 4; j++)
        pb[j] = gwpk + ((size_t)(rbB0 + j) * NKT_F * 64 + lane) * 8;

    f32x4 acc[4][4];
    const f32x4 zero = {0.f, 0.f, 0.f, 0.f};
#pragma unroll
    for (int i = 0; i < 4; i++)
#pragma unroll
        for (int j = 0; j < 4; j++) acc[i][j] = zero;

#pragma unroll
    for (int kt = 0; kt < NKT_F; ++kt) {
        bf16x8 af[4], bfr[4];
#pragma unroll
        for (int i = 0; i < 4; i++) af[i] = *(const bf16x8*)(pa[i] + (size_t)kt * 512);
#pragma unroll
        for (int j = 0; j < 4; j++) bfr[j] = *(const bf16x8*)(pb[j] + (size_t)kt * 512);
#pragma unroll
        for (int i = 0; i < 4; i++)
#pragma unroll
            for (int j = 0; j < 4; j++)
                acc[i][j] = __builtin_amdgcn_mfma_f32_16x16x32_bf16(af[i], bfr[j], acc[i][j], 0, 0, 0);
    }

    // epilogue: bias, ssq, LDS stash, coalesced packed stores
    float ss[4][4];
#pragma unroll
    for (int i = 0; i < 4; i++)
#pragma unroll
        for (int r = 0; r < 4; r++) ss[i][r] = 0.f;
#pragma unroll
    for (int j = 0; j < 4; j++) {
        const int lcbase = (wave & 1) * 64 + j * 16 + c;
        const float bias = gb[colTile * 128 + lcbase];
#pragma unroll
        for (int i = 0; i < 4; i++) {
#pragma unroll
            for (int r = 0; r < 4; r++) {
                const int lr = (wave >> 1) * 64 + i * 16 + q * 4 + r;
                const float v = acc[i][j][r] + bias;
                const unsigned short hb = bfbits(v);
                Es[lr * EPAD + lcbase] = hb;
                const float vs = bf2f(hb);
                ss[i][r] = fmaf(vs, vs, ss[i][r]);
            }
        }
    }
#pragma unroll
    for (int i = 0; i < 4; i++)
#pragma unroll
        for (int r = 0; r < 4; r++) {
            float s = ss[i][r];
            s += __shfl_xor(s, 1);
            s += __shfl_xor(s, 2);
            s += __shfl_xor(s, 4);
            s += __shfl_xor(s, 8);
            ss[i][r] = s;
        }
    if (c == 0) {
#pragma unroll
        for (int i = 0; i < 4; i++)
#pragma unroll
            for (int r = 0; r < 4; r++) {
                const int rowg = rowTile * 128 + (wave >> 1) * 64 + i * 16 + q * 4 + r;
                atomicAdd(&norm2[rowg], ss[i][r]);
            }
    }
    __syncthreads();

#pragma unroll
    for (int it = 0; it < 8; ++it) {
        const int m = it * 256 + tid;
        const int rbl = m >> 8;             // 0..7
        const int rest = m & 255;
        const int ktl = rest >> 6;          // 0..3
        const int lane2 = rest & 63;
        const int r2 = lane2 & 15;
        const int q2 = lane2 >> 4;
        const int lr = rbl * 16 + r2;
        const int lc = ktl * 32 + q2 * 8;
        const uint4 frag = *(const uint4*)(&Es[lr * EPAD + lc]);
        const size_t rb = (size_t)(rowTile * 8 + rbl);
        const size_t kte = (size_t)(colTile * 4 + ktl);
        *(uint4*)(embpk + ((rb * NKT_E + kte) * 64 + lane2) * 8) = frag;
    }
}

// ---------------------------------------------------------------------------
// Echo (packed, occ=4): barrier-free fragment GEMM, 8x8 supertile swizzle.
// Inline inv-norm^3 weights (finalize fused); last block computes the head
// (logits+sigmoid) via device-scope completion counter.
// ---------------------------------------------------------------------------
__global__ __launch_bounds__(256, 4) void echo_pk_kernel(
    const unsigned short* __restrict__ embpk, const float* __restrict__ norm2,
    const float* __restrict__ rvec, const float* __restrict__ hw,
    const float* __restrict__ hb, float* __restrict__ echo,
    unsigned int* __restrict__ cnt, float* __restrict__ out)
{
    __shared__ int lastFlag;
    const int tid = threadIdx.x, lane = tid & 63, wave = tid >> 6;
    const int q = lane >> 4, c = lane & 15;
    const int bid = blockIdx.x;          // 0..4095
    const int sb = bid >> 6, w = bid & 63;
    const int btile = (sb & 3) * 8 + (w & 7);    // 0..31
    const int ntile = (sb >> 2) * 8 + (w >> 3);  // 0..127
    const int row0 = btile * 128;
    const int col0 = ntile * 128;
    const int rbA0 = btile * 8 + (wave >> 1) * 4;
    const int rbB0 = 256 + ntile * 8 + (wave & 1) * 4;   // De rows start at rb 256

    const unsigned short* pa[4];
    const unsigned short* pb[4];
#pragma unroll
    for (int i = 0; i < 4; i++)
        pa[i] = embpk + ((size_t)(rbA0 + i) * NKT_E * 64 + lane) * 8;
#pragma unroll
    for (int j = 0; j < 4; j++)
        pb[j] = embpk + ((size_t)(rbB0 + j) * NKT_E * 64 + lane) * 8;

    f32x4 acc[4][4];
    const f32x4 zero = {0.f, 0.f, 0.f, 0.f};
#pragma unroll
    for (int i = 0; i < 4; i++)
#pragma unroll
        for (int j = 0; j < 4; j++) acc[i][j] = zero;

#pragma unroll
    for (int kt = 0; kt < NKT_E; ++kt) {
        bf16x8 af[4], bfr[4];
#pragma unroll
        for (int i = 0; i < 4; i++) af[i] = *(const bf16x8*)(pa[i] + (size_t)kt * 512);
#pragma unroll
        for (int j = 0; j < 4; j++) bfr[j] = *(const bf16x8*)(pb[j] + (size_t)kt * 512);
#pragma unroll
        for (int i = 0; i < 4; i++)
#pragma unroll
            for (int j = 0; j < 4; j++)
                acc[i][j] = __builtin_amdgcn_mfma_f32_16x16x32_bf16(af[i], bfr[j], acc[i][j], 0, 0, 0);
    }

    // epilogue: cube, weight by ind^3*(2r-1), reduce columns, atomicAdd rows
    float wc[4];
#pragma unroll
    for (int j = 0; j < 4; j++) {
        const int colg = col0 + (wave & 1) * 64 + j * 16 + c;   // D row index
        wc[j] = invn3(norm2[P_B + colg]) * (2.0f * rvec[colg] - 1.0f);
    }
    float p[4][4];
#pragma unroll
    for (int i = 0; i < 4; i++)
#pragma unroll
        for (int r = 0; r < 4; r++) p[i][r] = 0.f;
#pragma unroll
    for (int i = 0; i < 4; i++)
#pragma unroll
        for (int j = 0; j < 4; j++)
#pragma unroll
            for (int r = 0; r < 4; r++) {
                const float v = acc[i][j][r];
                const float v3 = v * v * v;
                p[i][r] = fmaf(v3, wc[j], p[i][r]);
            }
#pragma unroll
    for (int i = 0; i < 4; i++)
#pragma unroll
        for (int r = 0; r < 4; r++) {
            float s = p[i][r];
            s += __shfl_xor(s, 1);
            s += __shfl_xor(s, 2);
            s += __shfl_xor(s, 4);
            s += __shfl_xor(s, 8);
            p[i][r] = s;
        }
    if (c == 0) {
#pragma unroll
        for (int i = 0; i < 4; i++)
#pragma unroll
            for (int r = 0; r < 4; r++) {
                const int rowg = row0 + (wave >> 1) * 64 + i * 16 + q * 4 + r;
                atomicAdd(&echo[rowg], p[i][r] * invn3(norm2[rowg]));
            }
    }

    // fused head: last block to finish computes logits + sigmoid
    __syncthreads();                 // drains vmcnt -> this block's atomics done
    if (tid == 0) {
        __threadfence();
        const unsigned int old = atomicAdd(cnt, 1u);
        lastFlag = (old == 4095u);
    }
    __syncthreads();
    if (lastFlag) {
        __threadfence();
        const float hw0 = hw[0], hb0 = hb[0];
        for (int i = tid; i < P_B; i += 256) {
            const float e = atomicAdd(&echo[i], 0.0f);   // device-scope coherent read
            const float logit = fmaf(e, hw0, hb0);
            out[i] = logit;
            out[P_B + i] = 1.0f / (1.0f + expf(-logit));
        }
    }
}

extern "C" void kernel_launch(void* const* d_in, const int* in_sizes, int n_in,
                              void* d_out, int out_size, void* d_ws, size_t ws_size,
                              hipStream_t stream)
{
    const float* X  = (const float*)d_in[0];
    const float* D  = (const float*)d_in[1];
    const float* r  = (const float*)d_in[2];
    const float* gw = (const float*)d_in[3];
    const float* gb = (const float*)d_in[4];
    const float* hw = (const float*)d_in[5];
    const float* hb = (const float*)d_in[6];
    float* out = (float*)d_out;

    char* ws = (char*)d_ws;
    const size_t xdpk_bytes  = (size_t)1280 * NKT_F * 64 * 8 * 2;   // 31,457,280
    const size_t gwpk_bytes  = (size_t)32 * NKT_F * 64 * 8 * 2;     //    786,432
    const size_t embpk_bytes = (size_t)1280 * NKT_E * 64 * 8 * 2;   // 20,971,520

    unsigned short* xdpk  = (unsigned short*)ws;
    unsigned short* gwpk  = (unsigned short*)(ws + xdpk_bytes);
    unsigned short* embpk = (unsigned short*)(ws + xdpk_bytes + gwpk_bytes);
    float* norm2 = (float*)((char*)embpk + embpk_bytes);
    float* echo = norm2 + (P_B + P_N);
    unsigned int* cnt = (unsigned int*)(echo + P_B);

    convert_pack_kernel<<<dim3(1312), 256, 0, stream>>>(X, D, gw, xdpk, gwpk, norm2);
    embed_pk_kernel<<<dim3(640), 256, 0, stream>>>(xdpk, gwpk, gb, embpk, norm2);
    echo_pk_kernel<<<dim3(4096), 256, 0, stream>>>(embpk, norm2, r, hw, hb, echo, cnt, out);
}

// Round 8
// 274.051 us; speedup vs baseline: 1.4910x; 1.4910x over previous
//
#include <hip/hip_runtime.h>
#include <hip/hip_bf16.h>
#include <stdint.h>

#define P_B 4096
#define P_N 16384
#define P_F 768
#define P_E 512
#define NKT_F 24   // 768/32 k-tiles
#define NKT_E 16   // 512/32 k-tiles
#define CPAD 776   // convert LDS row pad (bf16 elems)
#define EPAD 136   // embed epilogue LDS row pad

typedef __attribute__((ext_vector_type(8))) __bf16 bf16x8;
typedef __attribute__((ext_vector_type(4))) float f32x4;

__device__ __forceinline__ unsigned short bfbits(float x) {
    __bf16 h = (__bf16)x;
    union { __bf16 h; unsigned short u; } cv;
    cv.h = h;
    return cv.u;
}
__device__ __forceinline__ float bf2f(unsigned short u) {
    union { float f; unsigned int i; } cv;
    cv.i = ((unsigned int)u) << 16;
    return cv.f;
}

// Fragment-packed layout: element (r,k) -> (((r>>4)*NKT + (k>>5))*64 +
// ((k>>3)&3)*16 + (r&15))*8 + (k&7). One wave fragment = contiguous 1KB.

// ---------------------------------------------------------------------------
// Convert+pack (+ zero-init of norm2/echo): fp32 row-major -> bf16
// fragment-packed via LDS transpose. Blocks 0..255 = X, 256..1279 = D,
// 1280..1311 = gw.
// ---------------------------------------------------------------------------
__global__ __launch_bounds__(256) void convert_pack_kernel(
    const float* __restrict__ X, const float* __restrict__ D,
    const float* __restrict__ gw,
    unsigned short* __restrict__ xdpk, unsigned short* __restrict__ gwpk,
    float* __restrict__ zbase)   // norm2(20480) | echo(4096)
{
    __shared__ unsigned short T[16 * CPAD];
    const int tid = threadIdx.x;
    const int rb = blockIdx.x;          // 0..1311

    if (rb < 97) {
        const int z = rb * 256 + tid;
        if (z < P_B + P_N + P_B) zbase[z] = 0.0f;
    }

    const float* src;
    unsigned short* dstbase;
    if (rb < 256)       { src = X  + (size_t)rb * 16 * P_F;          dstbase = xdpk + (size_t)rb * NKT_F * 512; }
    else if (rb < 1280) { src = D  + (size_t)(rb - 256) * 16 * P_F;  dstbase = xdpk + (size_t)rb * NKT_F * 512; }
    else                { src = gw + (size_t)(rb - 1280) * 16 * P_F; dstbase = gwpk + (size_t)(rb - 1280) * NKT_F * 512; }

#pragma unroll
    for (int it = 0; it < 12; ++it) {
        const int flat = it * 1024 + tid * 4;
        const int row = flat / P_F;
        const int col = flat - row * P_F;
        const float4 v = *(const float4*)(src + (size_t)row * P_F + col);
        unsigned short* t = &T[row * CPAD + col];
        t[0] = bfbits(v.x); t[1] = bfbits(v.y); t[2] = bfbits(v.z); t[3] = bfbits(v.w);
    }
    __syncthreads();

#pragma unroll
    for (int it = 0; it < 6; ++it) {
        const int m = it * 256 + tid;
        const int kt = m >> 6;          // 0..23
        const int lane = m & 63;
        const int r = lane & 15;
        const int k = kt * 32 + (lane >> 4) * 8;
        const uint4 frag = *(const uint4*)(&T[r * CPAD + k]);
        *(uint4*)(dstbase + (size_t)(kt * 64 + lane) * 8) = frag;
    }
}

// ---------------------------------------------------------------------------
// Embed (packed, XCD-swizzled): emb = xd·gw^T + gb. Barrier-free K-loop.
// bid&7 = XCD owns 20 rowTiles x all 4 colTiles -> A-slab (3.9MB) read ~once
// per XCD; gwpk (786KB) L2-resident. Epilogue: LDS transpose -> coalesced
// packed stores + per-row sum-of-squares.
// ---------------------------------------------------------------------------
__global__ __launch_bounds__(256, 3) void embed_pk_kernel(
    const unsigned short* __restrict__ xdpk, const unsigned short* __restrict__ gwpk,
    const float* __restrict__ gb,
    unsigned short* __restrict__ embpk, float* __restrict__ norm2)
{
    __shared__ unsigned short Es[128 * EPAD];
    const int tid = threadIdx.x, lane = tid & 63, wave = tid >> 6;
    const int q = lane >> 4, c = lane & 15;
    const int bid = blockIdx.x;                 // 0..639
    const int xcd = bid & 7;
    const int idx = bid >> 3;                   // 0..79
    const int rowTile = xcd * 20 + idx % 20;    // 0..159
    const int colTile = idx / 20;               // 0..3
    const int rbA0 = rowTile * 8 + (wave >> 1) * 4;
    const int rbB0 = colTile * 8 + (wave & 1) * 4;

    const unsigned short* pa[4];
    const unsigned short* pb[4];
#pragma unroll
    for (int i = 0; i < 4; i++)
        pa[i] = xdpk + ((size_t)(rbA0 + i) * NKT_F * 64 + lane) * 8;
#pragma unroll
    for (int j = 0; j < 4; j++)
        pb[j] = gwpk + ((size_t)(rbB0 + j) * NKT_F * 64 + lane) * 8;

    f32x4 acc[4][4];
    const f32x4 zero = {0.f, 0.f, 0.f, 0.f};
#pragma unroll
    for (int i = 0; i < 4; i++)
#pragma unroll
        for (int j = 0; j < 4; j++) acc[i][j] = zero;

#pragma unroll
    for (int kt = 0; kt < NKT_F; ++kt) {
        bf16x8 af[4], bfr[4];
#pragma unroll
        for (int i = 0; i < 4; i++) af[i] = *(const bf16x8*)(pa[i] + (size_t)kt * 512);
#pragma unroll
        for (int j = 0; j < 4; j++) bfr[j] = *(const bf16x8*)(pb[j] + (size_t)kt * 512);
#pragma unroll
        for (int i = 0; i < 4; i++)
#pragma unroll
            for (int j = 0; j < 4; j++)
                acc[i][j] = __builtin_amdgcn_mfma_f32_16x16x32_bf16(af[i], bfr[j], acc[i][j], 0, 0, 0);
    }

    // epilogue: bias, ssq, LDS stash, coalesced packed stores
    float ss[4][4];
#pragma unroll
    for (int i = 0; i < 4; i++)
#pragma unroll
        for (int r = 0; r < 4; r++) ss[i][r] = 0.f;
#pragma unroll
    for (int j = 0; j < 4; j++) {
        const int lcbase = (wave & 1) * 64 + j * 16 + c;
        const float bias = gb[colTile * 128 + lcbase];
#pragma unroll
        for (int i = 0; i < 4; i++) {
#pragma unroll
            for (int r = 0; r < 4; r++) {
                const int lr = (wave >> 1) * 64 + i * 16 + q * 4 + r;
                const float v = acc[i][j][r] + bias;
                const unsigned short hb = bfbits(v);
                Es[lr * EPAD + lcbase] = hb;
                const float vs = bf2f(hb);
                ss[i][r] = fmaf(vs, vs, ss[i][r]);
            }
        }
    }
#pragma unroll
    for (int i = 0; i < 4; i++)
#pragma unroll
        for (int r = 0; r < 4; r++) {
            float s = ss[i][r];
            s += __shfl_xor(s, 1);
            s += __shfl_xor(s, 2);
            s += __shfl_xor(s, 4);
            s += __shfl_xor(s, 8);
            ss[i][r] = s;
        }
    if (c == 0) {
#pragma unroll
        for (int i = 0; i < 4; i++)
#pragma unroll
            for (int r = 0; r < 4; r++) {
                const int rowg = rowTile * 128 + (wave >> 1) * 64 + i * 16 + q * 4 + r;
                atomicAdd(&norm2[rowg], ss[i][r]);
            }
    }
    __syncthreads();

#pragma unroll
    for (int it = 0; it < 8; ++it) {
        const int m = it * 256 + tid;
        const int rbl = m >> 8;             // 0..7
        const int rest = m & 255;
        const int ktl = rest >> 6;          // 0..3
        const int lane2 = rest & 63;
        const int r2 = lane2 & 15;
        const int q2 = lane2 >> 4;
        const int lr = rbl * 16 + r2;
        const int lc = ktl * 32 + q2 * 8;
        const uint4 frag = *(const uint4*)(&Es[lr * EPAD + lc]);
        const size_t rb = (size_t)(rowTile * 8 + rbl);
        const size_t kte = (size_t)(colTile * 4 + ktl);
        *(uint4*)(embpk + ((rb * NKT_E + kte) * 64 + lane2) * 8) = frag;
    }
}

// ---------------------------------------------------------------------------
// Finalize: norm2[i] -> inv_norm^3 (X rows), inv_norm^3 * (2r-1) (D rows)
// ---------------------------------------------------------------------------
__global__ void finalize_kernel(float* __restrict__ nf, const float* __restrict__ r)
{
    const int i = blockIdx.x * 256 + threadIdx.x;
    if (i >= P_B + P_N) return;
    float nrm = sqrtf(nf[i]);
    nrm = fmaxf(nrm, 1e-12f);
    const float inv = 1.0f / nrm;
    float w = inv * inv * inv;
    if (i >= P_B) {
        const float rv = r[i - P_B];
        w *= (2.0f * rv - 1.0f);
    }
    nf[i] = w;
}

// ---------------------------------------------------------------------------
// Echo (packed, r6 structure, occupancy 4): barrier-free fragment GEMM with
// 8x8 supertile swizzle. No fences, no fused head — those flush L2 (r7).
// ---------------------------------------------------------------------------
__global__ __launch_bounds__(256, 4) void echo_pk_kernel(
    const unsigned short* __restrict__ embpk, const float* __restrict__ fbuf,
    float* __restrict__ echo)
{
    const int tid = threadIdx.x, lane = tid & 63, wave = tid >> 6;
    const int q = lane >> 4, c = lane & 15;
    const int bid = blockIdx.x;          // 0..4095
    const int sb = bid >> 6, w = bid & 63;
    const int btile = (sb & 3) * 8 + (w & 7);    // 0..31
    const int ntile = (sb >> 2) * 8 + (w >> 3);  // 0..127
    const int row0 = btile * 128;
    const int col0 = ntile * 128;
    const int rbA0 = btile * 8 + (wave >> 1) * 4;
    const int rbB0 = 256 + ntile * 8 + (wave & 1) * 4;   // De rows start at rb 256

    const unsigned short* pa[4];
    const unsigned short* pb[4];
#pragma unroll
    for (int i = 0; i < 4; i++)
        pa[i] = embpk + ((size_t)(rbA0 + i) * NKT_E * 64 + lane) * 8;
#pragma unroll
    for (int j = 0; j < 4; j++)
        pb[j] = embpk + ((size_t)(rbB0 + j) * NKT_E * 64 + lane) * 8;

    f32x4 acc[4][4];
    const f32x4 zero = {0.f, 0.f, 0.f, 0.f};
#pragma unroll
    for (int i = 0; i < 4; i++)
#pragma unroll
        for (int j = 0; j < 4; j++) acc[i][j] = zero;

#pragma unroll
    for (int kt = 0; kt < NKT_E; ++kt) {
        bf16x8 af[4], bfr[4];
#pragma unroll
        for (int i = 0; i < 4; i++) af[i] = *(const bf16x8*)(pa[i] + (size_t)kt * 512);
#pragma unroll
        for (int j = 0; j < 4; j++) bfr[j] = *(const bf16x8*)(pb[j] + (size_t)kt * 512);
#pragma unroll
        for (int i = 0; i < 4; i++)
#pragma unroll
            for (int j = 0; j < 4; j++)
                acc[i][j] = __builtin_amdgcn_mfma_f32_16x16x32_bf16(af[i], bfr[j], acc[i][j], 0, 0, 0);
    }

    // epilogue: cube, weight by (ind^3*r2), reduce over columns, atomicAdd rows
    const float* fX = fbuf;
    const float* fD = fbuf + P_B;
    float wc[4];
#pragma unroll
    for (int j = 0; j < 4; j++) wc[j] = fD[col0 + (wave & 1) * 64 + j * 16 + c];
    float p[4][4];
#pragma unroll
    for (int i = 0; i < 4; i++)
#pragma unroll
        for (int r = 0; r < 4; r++) p[i][r] = 0.f;
#pragma unroll
    for (int i = 0; i < 4; i++)
#pragma unroll
        for (int j = 0; j < 4; j++)
#pragma unroll
            for (int r = 0; r < 4; r++) {
                const float v = acc[i][j][r];
                const float v3 = v * v * v;
                p[i][r] = fmaf(v3, wc[j], p[i][r]);
            }
#pragma unroll
    for (int i = 0; i < 4; i++)
#pragma unroll
        for (int r = 0; r < 4; r++) {
            float s = p[i][r];
            s += __shfl_xor(s, 1);
            s += __shfl_xor(s, 2);
            s += __shfl_xor(s, 4);
            s += __shfl_xor(s, 8);
            p[i][r] = s;
        }
    if (c == 0) {
#pragma unroll
        for (int i = 0; i < 4; i++)
#pragma unroll
            for (int r = 0; r < 4; r++) {
                const int rowg = row0 + (wave >> 1) * 64 + i * 16 + q * 4 + r;
                atomicAdd(&echo[rowg], p[i][r] * fX[rowg]);
            }
    }
}

// ---------------------------------------------------------------------------
// Head: logits = echo*h_w + h_b ; preds = sigmoid(logits)
// ---------------------------------------------------------------------------
__global__ void head_kernel(const float* __restrict__ echo, const float* __restrict__ hw,
                            const float* __restrict__ hb, float* __restrict__ out)
{
    const int i = blockIdx.x * 256 + threadIdx.x;
    if (i >= P_B) return;
    const float logit = fmaf(echo[i], hw[0], hb[0]);
    out[i] = logit;
    out[P_B + i] = 1.0f / (1.0f + expf(-logit));
}

extern "C" void kernel_launch(void* const* d_in, const int* in_sizes, int n_in,
                              void* d_out, int out_size, void* d_ws, size_t ws_size,
                              hipStream_t stream)
{
    const float* X  = (const float*)d_in[0];
    const float* D  = (const float*)d_in[1];
    const float* r  = (const float*)d_in[2];
    const float* gw = (const float*)d_in[3];
    const float* gb = (const float*)d_in[4];
    const float* hw = (const float*)d_in[5];
    const float* hb = (const float*)d_in[6];
    float* out = (float*)d_out;

    char* ws = (char*)d_ws;
    const size_t xdpk_bytes  = (size_t)1280 * NKT_F * 64 * 8 * 2;   // 31,457,280
    const size_t gwpk_bytes  = (size_t)32 * NKT_F * 64 * 8 * 2;     //    786,432
    const size_t embpk_bytes = (size_t)1280 * NKT_E * 64 * 8 * 2;   // 20,971,520

    unsigned short* xdpk  = (unsigned short*)ws;
    unsigned short* gwpk  = (unsigned short*)(ws + xdpk_bytes);
    unsigned short* embpk = (unsigned short*)(ws + xdpk_bytes + gwpk_bytes);
    float* norm2 = (float*)((char*)embpk + embpk_bytes);
    float* echo = norm2 + (P_B + P_N);

    convert_pack_kernel<<<dim3(1312), 256, 0, stream>>>(X, D, gw, xdpk, gwpk, norm2);
    embed_pk_kernel<<<dim3(640), 256, 0, stream>>>(xdpk, gwpk, gb, embpk, norm2);
    finalize_kernel<<<dim3((P_B + P_N + 255) / 256), 256, 0, stream>>>(norm2, r);
    echo_pk_kernel<<<dim3(4096), 256, 0, stream>>>(embpk, norm2, echo);
    head_kernel<<<dim3((P_B + 255) / 256), 256, 0, stream>>>(echo, hw, hb, out);
}

// Round 9
// 248.597 us; speedup vs baseline: 1.6436x; 1.1024x over previous
//
#include <hip/hip_runtime.h>
#include <hip/hip_bf16.h>
#include <stdint.h>

#define P_B 4096
#define P_N 16384
#define P_F 768
#define P_E 512
#define NKT_F 24   // 768/32 k-tiles
#define NKT_E 16   // 512/32 k-tiles
#define CPAD 776   // convert LDS row pad (bf16 elems)
#define EPAD 136   // embed epilogue LDS row pad

typedef __attribute__((ext_vector_type(8))) __bf16 bf16x8;
typedef __attribute__((ext_vector_type(4))) float f32x4;

__device__ __forceinline__ unsigned short bfbits(float x) {
    __bf16 h = (__bf16)x;
    union { __bf16 h; unsigned short u; } cv;
    cv.h = h;
    return cv.u;
}
__device__ __forceinline__ float bf2f(unsigned short u) {
    union { float f; unsigned int i; } cv;
    cv.i = ((unsigned int)u) << 16;
    return cv.f;
}

// Fragment-packed layout: element (r,k) -> (((r>>4)*NKT + (k>>5))*64 +
// ((k>>3)&3)*16 + (r&15))*8 + (k&7). One wave fragment = contiguous 1KB.

// ---------------------------------------------------------------------------
// Convert+pack (+ zero-init of norm2/echo): fp32 row-major -> bf16
// fragment-packed via LDS transpose. Blocks 0..255 = X, 256..1279 = D,
// 1280..1311 = gw.
// ---------------------------------------------------------------------------
__global__ __launch_bounds__(256) void convert_pack_kernel(
    const float* __restrict__ X, const float* __restrict__ D,
    const float* __restrict__ gw,
    unsigned short* __restrict__ xdpk, unsigned short* __restrict__ gwpk,
    float* __restrict__ zbase)   // norm2(20480) | echo(4096)
{
    __shared__ unsigned short T[16 * CPAD];
    const int tid = threadIdx.x;
    const int rb = blockIdx.x;          // 0..1311

    if (rb < 97) {
        const int z = rb * 256 + tid;
        if (z < P_B + P_N + P_B) zbase[z] = 0.0f;
    }

    const float* src;
    unsigned short* dstbase;
    if (rb < 256)       { src = X  + (size_t)rb * 16 * P_F;          dstbase = xdpk + (size_t)rb * NKT_F * 512; }
    else if (rb < 1280) { src = D  + (size_t)(rb - 256) * 16 * P_F;  dstbase = xdpk + (size_t)rb * NKT_F * 512; }
    else                { src = gw + (size_t)(rb - 1280) * 16 * P_F; dstbase = gwpk + (size_t)(rb - 1280) * NKT_F * 512; }

#pragma unroll
    for (int it = 0; it < 12; ++it) {
        const int flat = it * 1024 + tid * 4;
        const int row = flat / P_F;
        const int col = flat - row * P_F;
        const float4 v = *(const float4*)(src + (size_t)row * P_F + col);
        unsigned short* t = &T[row * CPAD + col];
        t[0] = bfbits(v.x); t[1] = bfbits(v.y); t[2] = bfbits(v.z); t[3] = bfbits(v.w);
    }
    __syncthreads();

#pragma unroll
    for (int it = 0; it < 6; ++it) {
        const int m = it * 256 + tid;
        const int kt = m >> 6;          // 0..23
        const int lane = m & 63;
        const int r = lane & 15;
        const int k = kt * 32 + (lane >> 4) * 8;
        const uint4 frag = *(const uint4*)(&T[r * CPAD + k]);
        *(uint4*)(dstbase + (size_t)(kt * 64 + lane) * 8) = frag;
    }
}

// ---------------------------------------------------------------------------
// Embed (packed, XCD-swizzled): emb = xd·gw^T + gb. Barrier-free K-loop.
// bid&7 = XCD owns 20 rowTiles x all 4 colTiles; gwpk (786KB) L2-resident.
// Epilogue: LDS transpose -> coalesced packed stores + per-row ssq.
// ---------------------------------------------------------------------------
__global__ __launch_bounds__(256, 3) void embed_pk_kernel(
    const unsigned short* __restrict__ xdpk, const unsigned short* __restrict__ gwpk,
    const float* __restrict__ gb,
    unsigned short* __restrict__ embpk, float* __restrict__ norm2)
{
    __shared__ unsigned short Es[128 * EPAD];
    const int tid = threadIdx.x, lane = tid & 63, wave = tid >> 6;
    const int q = lane >> 4, c = lane & 15;
    const int bid = blockIdx.x;                 // 0..639
    const int xcd = bid & 7;
    const int idx = bid >> 3;                   // 0..79
    const int rowTile = xcd * 20 + idx % 20;    // 0..159
    const int colTile = idx / 20;               // 0..3
    const int rbA0 = rowTile * 8 + (wave >> 1) * 4;
    const int rbB0 = colTile * 8 + (wave & 1) * 4;

    const unsigned short* pa[4];
    const unsigned short* pb[4];
#pragma unroll
    for (int i = 0; i < 4; i++)
        pa[i] = xdpk + ((size_t)(rbA0 + i) * NKT_F * 64 + lane) * 8;
#pragma unroll
    for (int j = 0; j < 4; j++)
        pb[j] = gwpk + ((size_t)(rbB0 + j) * NKT_F * 64 + lane) * 8;

    f32x4 acc[4][4];
    const f32x4 zero = {0.f, 0.f, 0.f, 0.f};
#pragma unroll
    for (int i = 0; i < 4; i++)
#pragma unroll
        for (int j = 0; j < 4; j++) acc[i][j] = zero;

#pragma unroll
    for (int kt = 0; kt < NKT_F; ++kt) {
        bf16x8 af[4], bfr[4];
#pragma unroll
        for (int i = 0; i < 4; i++) af[i] = *(const bf16x8*)(pa[i] + (size_t)kt * 512);
#pragma unroll
        for (int j = 0; j < 4; j++) bfr[j] = *(const bf16x8*)(pb[j] + (size_t)kt * 512);
#pragma unroll
        for (int i = 0; i < 4; i++)
#pragma unroll
            for (int j = 0; j < 4; j++)
                acc[i][j] = __builtin_amdgcn_mfma_f32_16x16x32_bf16(af[i], bfr[j], acc[i][j], 0, 0, 0);
    }

    // epilogue: bias, ssq, LDS stash, coalesced packed stores
    float ss[4][4];
#pragma unroll
    for (int i = 0; i < 4; i++)
#pragma unroll
        for (int r = 0; r < 4; r++) ss[i][r] = 0.f;
#pragma unroll
    for (int j = 0; j < 4; j++) {
        const int lcbase = (wave & 1) * 64 + j * 16 + c;
        const float bias = gb[colTile * 128 + lcbase];
#pragma unroll
        for (int i = 0; i < 4; i++) {
#pragma unroll
            for (int r = 0; r < 4; r++) {
                const int lr = (wave >> 1) * 64 + i * 16 + q * 4 + r;
                const float v = acc[i][j][r] + bias;
                const unsigned short hb = bfbits(v);
                Es[lr * EPAD + lcbase] = hb;
                const float vs = bf2f(hb);
                ss[i][r] = fmaf(vs, vs, ss[i][r]);
            }
        }
    }
#pragma unroll
    for (int i = 0; i < 4; i++)
#pragma unroll
        for (int r = 0; r < 4; r++) {
            float s = ss[i][r];
            s += __shfl_xor(s, 1);
            s += __shfl_xor(s, 2);
            s += __shfl_xor(s, 4);
            s += __shfl_xor(s, 8);
            ss[i][r] = s;
        }
    if (c == 0) {
#pragma unroll
        for (int i = 0; i < 4; i++)
#pragma unroll
            for (int r = 0; r < 4; r++) {
                const int rowg = rowTile * 128 + (wave >> 1) * 64 + i * 16 + q * 4 + r;
                atomicAdd(&norm2[rowg], ss[i][r]);
            }
    }
    __syncthreads();

#pragma unroll
    for (int it = 0; it < 8; ++it) {
        const int m = it * 256 + tid;
        const int rbl = m >> 8;             // 0..7
        const int rest = m & 255;
        const int ktl = rest >> 6;          // 0..3
        const int lane2 = rest & 63;
        const int r2 = lane2 & 15;
        const int q2 = lane2 >> 4;
        const int lr = rbl * 16 + r2;
        const int lc = ktl * 32 + q2 * 8;
        const uint4 frag = *(const uint4*)(&Es[lr * EPAD + lc]);
        const size_t rb = (size_t)(rowTile * 8 + rbl);
        const size_t kte = (size_t)(colTile * 4 + ktl);
        *(uint4*)(embpk + ((rb * NKT_E + kte) * 64 + lane2) * 8) = frag;
    }
}

// ---------------------------------------------------------------------------
// Finalize: norm2[i] -> inv_norm^3 (X rows), inv_norm^3 * (2r-1) (D rows)
// ---------------------------------------------------------------------------
__global__ void finalize_kernel(float* __restrict__ nf, const float* __restrict__ r)
{
    const int i = blockIdx.x * 256 + threadIdx.x;
    if (i >= P_B + P_N) return;
    float nrm = sqrtf(nf[i]);
    nrm = fmaxf(nrm, 1e-12f);
    const float inv = 1.0f / nrm;
    float w = inv * inv * inv;
    if (i >= P_B) {
        const float rv = r[i - P_B];
        w *= (2.0f * rv - 1.0f);
    }
    nf[i] = w;
}

// ---------------------------------------------------------------------------
// Echo v6: 128x256 block tile (per-wave 64x128, acc=128 regs, occupancy 2 —
// NOT 4: r8 proved >2 spills). Barrier-free packed fragment loads.
// XCD B-residency: bid&7 = XCD owns 8 ntiles (2MB B-slab hot in its L2),
// A (4MB) streams. Raises AI per block 1.5x vs 128x128 (L2-BW-bound fix).
// ---------------------------------------------------------------------------
__global__ __launch_bounds__(256, 2) void echo_pk_kernel(
    const unsigned short* __restrict__ embpk, const float* __restrict__ fbuf,
    float* __restrict__ echo)
{
    const int tid = threadIdx.x, lane = tid & 63, wave = tid >> 6;
    const int q = lane >> 4, c = lane & 15;
    const int bid = blockIdx.x;          // 0..2047
    const int xcd = bid & 7;
    const int idx = bid >> 3;            // 0..255
    const int ntile = xcd * 8 + (idx & 7);   // 0..63 (256-wide col tiles)
    const int btile = idx >> 3;              // 0..31
    const int wr = wave >> 1, wc2 = wave & 1;
    const int row0 = btile * 128;
    const int col0 = ntile * 256;
    const int rbA0 = btile * 8 + wr * 4;
    const int rbB0 = 256 + ntile * 16 + wc2 * 8;   // De rows start at rb 256

    const unsigned short* pa[4];
    const unsigned short* pb[8];
#pragma unroll
    for (int i = 0; i < 4; i++)
        pa[i] = embpk + ((size_t)(rbA0 + i) * NKT_E * 64 + lane) * 8;
#pragma unroll
    for (int j = 0; j < 8; j++)
        pb[j] = embpk + ((size_t)(rbB0 + j) * NKT_E * 64 + lane) * 8;

    f32x4 acc[4][8];
    const f32x4 zero = {0.f, 0.f, 0.f, 0.f};
#pragma unroll
    for (int i = 0; i < 4; i++)
#pragma unroll
        for (int j = 0; j < 8; j++) acc[i][j] = zero;

#pragma unroll
    for (int kt = 0; kt < NKT_E; ++kt) {
        bf16x8 af[4], bfr[8];
#pragma unroll
        for (int i = 0; i < 4; i++) af[i] = *(const bf16x8*)(pa[i] + (size_t)kt * 512);
#pragma unroll
        for (int j = 0; j < 8; j++) bfr[j] = *(const bf16x8*)(pb[j] + (size_t)kt * 512);
#pragma unroll
        for (int i = 0; i < 4; i++)
#pragma unroll
            for (int j = 0; j < 8; j++)
                acc[i][j] = __builtin_amdgcn_mfma_f32_16x16x32_bf16(af[i], bfr[j], acc[i][j], 0, 0, 0);
    }

    // epilogue: cube, weight by (ind^3*r2), reduce over columns, atomicAdd rows
    const float* fX = fbuf;
    const float* fD = fbuf + P_B;
    float wc[8];
#pragma unroll
    for (int j = 0; j < 8; j++) wc[j] = fD[col0 + wc2 * 128 + j * 16 + c];
    float p[4][4];
#pragma unroll
    for (int i = 0; i < 4; i++)
#pragma unroll
        for (int r = 0; r < 4; r++) p[i][r] = 0.f;
#pragma unroll
    for (int i = 0; i < 4; i++)
#pragma unroll
        for (int j = 0; j < 8; j++)
#pragma unroll
            for (int r = 0; r < 4; r++) {
                const float v = acc[i][j][r];
                const float v3 = v * v * v;
                p[i][r] = fmaf(v3, wc[j], p[i][r]);
            }
#pragma unroll
    for (int i = 0; i < 4; i++)
#pragma unroll
        for (int r = 0; r < 4; r++) {
            float s = p[i][r];
            s += __shfl_xor(s, 1);
            s += __shfl_xor(s, 2);
            s += __shfl_xor(s, 4);
            s += __shfl_xor(s, 8);
            p[i][r] = s;
        }
    if (c == 0) {
#pragma unroll
        for (int i = 0; i < 4; i++)
#pragma unroll
            for (int r = 0; r < 4; r++) {
                const int rowg = row0 + wr * 64 + i * 16 + q * 4 + r;
                atomicAdd(&echo[rowg], p[i][r] * fX[rowg]);
            }
    }
}

// ---------------------------------------------------------------------------
// Head: logits = echo*h_w + h_b ; preds = sigmoid(logits)
// ---------------------------------------------------------------------------
__global__ void head_kernel(const float* __restrict__ echo, const float* __restrict__ hw,
                            const float* __restrict__ hb, float* __restrict__ out)
{
    const int i = blockIdx.x * 256 + threadIdx.x;
    if (i >= P_B) return;
    const float logit = fmaf(echo[i], hw[0], hb[0]);
    out[i] = logit;
    out[P_B + i] = 1.0f / (1.0f + expf(-logit));
}

extern "C" void kernel_launch(void* const* d_in, const int* in_sizes, int n_in,
                              void* d_out, int out_size, void* d_ws, size_t ws_size,
                              hipStream_t stream)
{
    const float* X  = (const float*)d_in[0];
    const float* D  = (const float*)d_in[1];
    const float* r  = (const float*)d_in[2];
    const float* gw = (const float*)d_in[3];
    const float* gb = (const float*)d_in[4];
    const float* hw = (const float*)d_in[5];
    const float* hb = (const float*)d_in[6];
    float* out = (float*)d_out;

    char* ws = (char*)d_ws;
    const size_t xdpk_bytes  = (size_t)1280 * NKT_F * 64 * 8 * 2;   // 31,457,280
    const size_t gwpk_bytes  = (size_t)32 * NKT_F * 64 * 8 * 2;     //    786,432
    const size_t embpk_bytes = (size_t)1280 * NKT_E * 64 * 8 * 2;   // 20,971,520

    unsigned short* xdpk  = (unsigned short*)ws;
    unsigned short* gwpk  = (unsigned short*)(ws + xdpk_bytes);
    unsigned short* embpk = (unsigned short*)(ws + xdpk_bytes + gwpk_bytes);
    float* norm2 = (float*)((char*)embpk + embpk_bytes);
    float* echo = norm2 + (P_B + P_N);

    convert_pack_kernel<<<dim3(1312), 256, 0, stream>>>(X, D, gw, xdpk, gwpk, norm2);
    embed_pk_kernel<<<dim3(640), 256, 0, stream>>>(xdpk, gwpk, gb, embpk, norm2);
    finalize_kernel<<<dim3((P_B + P_N + 255) / 256), 256, 0, stream>>>(norm2, r);
    echo_pk_kernel<<<dim3(2048), 256, 0, stream>>>(embpk, norm2, echo);
    head_kernel<<<dim3((P_B + 255) / 256), 256, 0, stream>>>(echo, hw, hb, out);
}